// Round 14
// baseline (51.405 us; speedup 1.0000x reference)
//
#include <hip/hip_runtime.h>
#include <stdint.h>

#define N_PTS 4096
#define BATCH 4
#define C_IN  128
#define C_OUT 256
#define KDIM  1024   // 8 active slots * 128 channels (octant-7 slot provably always zero)
#define NCELL 512    // 8x8x8 spatial grid, cell 0.125 >= radius 0.12
#define BIGJ  0x3fffffff

typedef __attribute__((ext_vector_type(8))) __bf16 bf16x8;
typedef __attribute__((ext_vector_type(4))) float  f32x4;

__device__ inline void gload_lds16(const void* g, void* l) {
    __builtin_amdgcn_global_load_lds(
        (__attribute__((address_space(1))) void*)(void*)(uintptr_t)g,
        (__attribute__((address_space(3))) void*)l, 16, 0, 0);
}

__device__ inline unsigned short f2bf(float v) {
    uint32_t u = __builtin_bit_cast(uint32_t, v);
    return (unsigned short)((u + 0x7fffu + ((u >> 16) & 1u)) >> 16);   // RTNE
}

// reference-exact sq = ((x*x + y*y) + z*z), no FMA contraction
__device__ inline float sq_exact(float x, float y, float z) {
    return __fadd_rn(__fadd_rn(__fmul_rn(x, x), __fmul_rn(y, y)), __fmul_rn(z, z));
}

__device__ inline int cell_of(float x, float y, float z) {
    int cx = (int)(x * 8.0f); cx = min(max(cx, 0), 7);
    int cy = (int)(y * 8.0f); cy = min(max(cy, 0), 7);
    int cz = (int)(z * 8.0f); cz = min(max(cz, 0), 7);
    return (cx << 6) | (cy << 3) | cz;
}

__device__ inline int wmin(int v) {
    for (int off = 32; off >= 1; off >>= 1) v = min(v, __shfl_xor(v, off, 64));
    return v;
}

// ---------------- kernel 1: fused prep (unchanged from round 13) ----------------
// NOTE: launched TWICE this round as a timing probe — idempotent: wt/xbf are pure
// functions; cellstart deterministic; sp4 fully overwritten (any intra-cell
// permutation is valid; bq's output is permutation-invariant, proven R5+).
__global__ __launch_bounds__(256) void fused_prep(const float* __restrict__ w,
                                                  unsigned short* __restrict__ wt,
                                                  const float* __restrict__ x,
                                                  unsigned short* __restrict__ xbf,
                                                  const float* __restrict__ pcs,
                                                  float4* __restrict__ sp4,
                                                  int* __restrict__ cellstart) {
    const int bid = blockIdx.x;
    const int tid = threadIdx.x;

    if (bid < 4) {
        // ---- grid build for batch b: count -> prefix -> scatter (LDS) ----
        __shared__ int scnt[NCELL];                   // counts -> cursors
        __shared__ int pairs[256];
        const int b = bid;
        const float* pb = pcs + (size_t)b * 3 * N_PTS;
        for (int i = tid; i < NCELL; i += 256) scnt[i] = 0;
        float px[16], py[16], pz[16];
#pragma unroll
        for (int k = 0; k < 16; ++k) {
            int n = k * 256 + tid;
            px[k] = pb[n]; py[k] = pb[N_PTS + n]; pz[k] = pb[2 * N_PTS + n];
        }
        __syncthreads();
#pragma unroll
        for (int k = 0; k < 16; ++k)
            atomicAdd(&scnt[cell_of(px[k], py[k], pz[k])], 1);
        __syncthreads();
        const int a0 = scnt[2 * tid], a1 = scnt[2 * tid + 1];
        pairs[tid] = a0 + a1;
        __syncthreads();
        for (int off = 1; off < 256; off <<= 1) {
            int v = (tid >= off) ? pairs[tid - off] : 0;
            __syncthreads();
            pairs[tid] += v;
            __syncthreads();
        }
        const int epair = pairs[tid] - (a0 + a1);     // exclusive pair prefix
        cellstart[b * 513 + 2 * tid]     = epair;
        cellstart[b * 513 + 2 * tid + 1] = epair + a0;
        scnt[2 * tid]     = epair;                    // cursors
        scnt[2 * tid + 1] = epair + a0;
        if (tid == 255) cellstart[b * 513 + 512] = epair + a0 + a1;
        __syncthreads();
#pragma unroll
        for (int k = 0; k < 16; ++k) {
            int n = k * 256 + tid;
            int slot = atomicAdd(&scnt[cell_of(px[k], py[k], pz[k])], 1);
            sp4[(b << 12) + slot] =
                make_float4(px[k], py[k], pz[k], __builtin_bit_cast(float, n));
        }
    } else if (bid < 260) {
        // ---- weight transpose: one block per o ----
        __shared__ float wrow[1152];
        const int o = bid - 4;
        for (int i = tid; i < 1152; i += 256)
            wrow[i] = w[(size_t)o * 1152 + i];        // fully coalesced
        __syncthreads();
        const int k0 = tid * 4;                       // 4 consecutive kappa
        unsigned int lo =
            (unsigned int)f2bf(wrow[((k0    ) & 127) * 9 + ((k0    ) >> 7)]) |
            ((unsigned int)f2bf(wrow[((k0 + 1) & 127) * 9 + ((k0 + 1) >> 7)]) << 16);
        unsigned int hi =
            (unsigned int)f2bf(wrow[((k0 + 2) & 127) * 9 + ((k0 + 2) >> 7)]) |
            ((unsigned int)f2bf(wrow[((k0 + 3) & 127) * 9 + ((k0 + 3) >> 7)]) << 16);
        *(uint2*)&wt[(size_t)o * 1024 + k0] = make_uint2(lo, hi);
    } else {
        // ---- feature transpose: float4 loads, c-major tile ----
        __shared__ __attribute__((aligned(16))) unsigned short tcj[128 * 66];
        const int bb = bid - 260;
        const int b = bb / 65;
        const int j0 = (bb % 65) * 64;
        if (j0 < N_PTS) {
            const int p = tid & 15;                   // j4 = p*4 (16 lanes cover 64 j)
            const int g = tid >> 4;                   // 16 channel-groups
#pragma unroll
            for (int it = 0; it < 8; ++it) {
                const int cc = it * 16 + g;
                float4 v = *(const float4*)&x[((size_t)b * C_IN + cc) * N_PTS + j0 + p * 4];
                unsigned int lo = (unsigned int)f2bf(v.x) | ((unsigned int)f2bf(v.y) << 16);
                unsigned int hi = (unsigned int)f2bf(v.z) | ((unsigned int)f2bf(v.w) << 16);
                *(uint2*)&tcj[cc * 66 + p * 4] = make_uint2(lo, hi);
            }
            __syncthreads();
#pragma unroll
            for (int i = 0; i < 8; ++i) {
                int idx = i * 256 + tid;              // 2048 uint2: 64 j x 32 c-quads
                int row = idx >> 5, cq = idx & 31;
                unsigned int lo =
                    (unsigned int)tcj[(cq * 4 + 0) * 66 + row] |
                    ((unsigned int)tcj[(cq * 4 + 1) * 66 + row] << 16);
                unsigned int hi =
                    (unsigned int)tcj[(cq * 4 + 2) * 66 + row] |
                    ((unsigned int)tcj[(cq * 4 + 3) * 66 + row] << 16);
                *(uint2*)&xbf[((size_t)b * (N_PTS + 1) + j0 + row) * C_IN + cq * 4] =
                    make_uint2(lo, hi);
            }
        } else {
            // zeros row j = 4096 (empty-octant gather target)
            for (int i = tid; i < C_IN; i += 256)
                xbf[((size_t)b * (N_PTS + 1) + N_PTS) * C_IN + i] = 0;
        }
    }
}

// ---------------- kernel 2: grid ball query (unchanged from round 9/12) -------------
__global__ __launch_bounds__(256) void bq_grid(const float4* __restrict__ sp4,
                                               const int* __restrict__ cellstart,
                                               unsigned short* __restrict__ idxu) {
    __shared__ int lists[4 * 128];
    const int tid = threadIdx.x;
    const int wid = tid >> 6, lane = tid & 63;
    // XCD-chunked bijective swizzle (4096 blocks, 8 XCDs)
    const int lb = ((blockIdx.x & 7) << 9) | (blockIdx.x >> 3);
    const int gw = (lb << 2) | wid;                   // global wave id 0..16383
    const int b = gw >> 12;
    const int sidx = gw & 4095;                       // cell-sorted slot
    const float4* sp = sp4 + ((size_t)b << 12);
    const int* cs = cellstart + b * 513;
    const float4 cp = sp[sidx];
    const float cxf = cp.x, cyf = cp.y, czf = cp.z;
    const int n = __builtin_bit_cast(int, cp.w);      // original center index
    const float csq = sq_exact(cxf, cyf, czf);        // bit-identical to reference
    const float r2 = (float)(0.12 * 0.12);

    int cx = min(max((int)(cxf * 8.0f), 0), 7);
    int cy = min(max((int)(cyf * 8.0f), 0), 7);
    int cz = min(max((int)(czf * 8.0f), 0), 7);
    const int zlo = max(cz - 1, 0), zhi = min(cz + 1, 7);

    // 9-run table (wave-uniform scalars, static names only — rule #20)
#define RUN(k, dx, dy)                                                              \
    int rs##k = 0, ln##k = 0;                                                       \
    {                                                                               \
        int gx = cx + (dx), gy = cy + (dy);                                         \
        if (gx >= 0 && gx <= 7 && gy >= 0 && gy <= 7) {                             \
            int cb_ = (gx << 6) | (gy << 3);                                        \
            rs##k = cs[cb_ + zlo];                                                  \
            ln##k = cs[cb_ + zhi + 1] - rs##k;                                      \
        }                                                                           \
    }
    RUN(0, -1, -1) RUN(1, -1, 0) RUN(2, -1, 1)
    RUN(3,  0, -1) RUN(4,  0, 0) RUN(5,  0, 1)
    RUN(6,  1, -1) RUN(7,  1, 0) RUN(8,  1, 1)
#undef RUN
    const int c1 = ln0;
    const int c2 = c1 + ln1;
    const int c3 = c2 + ln2;
    const int c4 = c3 + ln3;
    const int c5 = c4 + ln4;
    const int c6 = c5 + ln5;
    const int c7 = c6 + ln6;
    const int c8 = c7 + ln7;
    const int TT = c8 + ln8;                          // total candidates (~216 avg)

    // stream position -> cell-sorted slot (static cndmask chain, clamped safe)
#define CAND_IDX(T, OUTI)                                                           \
    {                                                                               \
        const int t_ = (T);                                                         \
        int i_ = rs0 + t_;                                                          \
        i_ = (t_ >= c1) ? (rs1 + t_ - c1) : i_;                                     \
        i_ = (t_ >= c2) ? (rs2 + t_ - c2) : i_;                                     \
        i_ = (t_ >= c3) ? (rs3 + t_ - c3) : i_;                                     \
        i_ = (t_ >= c4) ? (rs4 + t_ - c4) : i_;                                     \
        i_ = (t_ >= c5) ? (rs5 + t_ - c5) : i_;                                     \
        i_ = (t_ >= c6) ? (rs6 + t_ - c6) : i_;                                     \
        i_ = (t_ >= c7) ? (rs7 + t_ - c7) : i_;                                     \
        i_ = (t_ >= c8) ? (rs8 + t_ - c8) : i_;                                     \
        OUTI = (t_ < TT) ? i_ : rs4;   /* rs4 = center's own cell, always valid */  \
    }

    int f0 = BIGJ, f1 = BIGJ, f2 = BIGJ, f3 = BIGJ, f4 = BIGJ, f5 = BIGJ, f6 = BIGJ;
    int cnt = 0;
    int* lst = &lists[wid * 128];
    const unsigned long long ltm = (1ull << lane) - 1ull;

    int ic0;
    CAND_IDX(lane, ic0)
    float4 p_cur = sp[ic0];                           // prologue load (TT >= 1 always)

    for (int t0 = 0; t0 < TT; t0 += 64) {
        int icn;
        CAND_IDX(t0 + 64 + lane, icn)
        const float4 p_nxt = sp[icn];                 // prefetch next chunk

        const bool valid = (t0 + lane) < TT;
        const float4 p = p_cur;
        const int j = __builtin_bit_cast(int, p.w);
        const float psq = sq_exact(p.x, p.y, p.z);    // bit-identical to reference
        float dot = __fadd_rn(__fadd_rn(__fmul_rn(cxf, p.x), __fmul_rn(cyf, p.y)),
                              __fmul_rn(czf, p.z));
        float dd = __fsub_rn(__fadd_rn(csq, psq), __fmul_rn(2.0f, dot));
        const bool ok = valid && (dd <= r2) && (j != n);
        unsigned long long m = __ballot(ok);
        if (m) {
            int pos = cnt + __popcll(m & ltm);
            if (ok && pos < 128) lst[pos] = j;
            cnt += __popcll(m);
            const int oct = ((p.x >= cxf) ? 4 : 0) + ((p.y >= cyf) ? 2 : 0)
                          + ((p.z >= czf) ? 1 : 0);
            const int key = ok ? j : BIGJ;
            f0 = (oct == 0) ? min(f0, key) : f0;
            f1 = (oct == 1) ? min(f1, key) : f1;
            f2 = (oct == 2) ? min(f2, key) : f2;
            f3 = (oct == 3) ? min(f3, key) : f3;
            f4 = (oct == 4) ? min(f4, key) : f4;
            f5 = (oct == 5) ? min(f5, key) : f5;
            f6 = (oct == 6) ? min(f6, key) : f6;
        }
        p_cur = p_nxt;
    }
#undef CAND_IDX

    f0 = wmin(f0); f1 = wmin(f1); f2 = wmin(f2); f3 = wmin(f3);
    f4 = wmin(f4); f5 = wmin(f5); f6 = wmin(f6);

    if (cnt > 31) {
        // rank check against the (<=128) recorded matches; cnt>128 has ~0
        // probability at lambda~30 (same exposure as the sort it replaced)
        const int c2_ = min(cnt, 128);
        const int l0 = (lane < c2_) ? lst[lane] : BIGJ;
        const int l1 = (64 + lane < c2_) ? lst[64 + lane] : BIGJ;
#define RANKCHK(F)                                                                  \
        {                                                                           \
            int r_ = __popcll(__ballot(l0 < F)) + __popcll(__ballot(l1 < F));       \
            F = (r_ <= 30) ? F : BIGJ;                                              \
        }
        RANKCHK(f0) RANKCHK(f1) RANKCHK(f2) RANKCHK(f3)
        RANKCHK(f4) RANKCHK(f5) RANKCHK(f6)
#undef RANKCHK
    }

    int v = n;                                        // lane 0: center index
    if (lane == 1) v = f0;
    if (lane == 2) v = f1;
    if (lane == 3) v = f2;
    if (lane == 4) v = f3;
    if (lane == 5) v = f4;
    if (lane == 6) v = f5;
    if (lane == 7) v = f6;
    if (v > N_PTS) v = N_PTS;                         // BIGJ -> zeros row
    if (lane < 8) idxu[((size_t)((b << 12) | n)) * 8 + lane] = (unsigned short)v;
}

// ---------------- kernel 3: gathered GEMM (unchanged from round 12) ----------------
__global__ __launch_bounds__(512) void pconv_gemm(const unsigned short* __restrict__ xbf,
                                                  const unsigned short* __restrict__ wt,
                                                  const unsigned short* __restrict__ idxu,
                                                  const float* __restrict__ bias,
                                                  float* __restrict__ out) {
    __shared__ __attribute__((aligned(16))) unsigned short Plds[2][128 * 64];
    __shared__ __attribute__((aligned(16))) unsigned short Wlds[2][128 * 64];
    __shared__ unsigned short jlds[128 * 8];
    const int tid = threadIdx.x;
    const int tile = ((blockIdx.x & 7) << 5) | (blockIdx.x >> 3);   // XCD-chunked, bijective
    const int tm = tile >> 1, tn = tile & 1;  // 128 M-tiles x 2 N-tiles
    const int g0 = tm * 128;                 // global point-row base
    const int b  = g0 >> 12;
    const int nb = g0 & 4095;
    const int o0 = tn * 128;
    const int wid = tid >> 6, lane = tid & 63;
    const int wo = wid >> 1, wn = wid & 1;   // wave -> 32 o-rows x 64 n-cols

    // hoist all gather indices for this block (1024 u16, coalesced)
    for (int i = tid; i < 1024; i += 512) jlds[i] = idxu[(size_t)g0 * 8 + i];
    __syncthreads();

    f32x4 acc[2][4] = {};

#define STAGE(BUF, IT)                                                              \
    {                                                                               \
        const int k0_ = (IT) << 6;                                                  \
        const int slot_ = (IT) >> 1;                                                \
        const int cb_ = ((IT) & 1) << 6;                                            \
        _Pragma("unroll")                                                           \
        for (int i_ = 0; i_ < 2; ++i_) {                                            \
            const int Lb_ = i_ * 512 + wid * 64;                                    \
            const int row_ = (Lb_ + lane) >> 3;                                     \
            const int slog_ = (lane & 7) ^ (row_ & 7);                              \
            int j_ = jlds[row_ * 8 + slot_];                                        \
            gload_lds16(xbf + ((size_t)b * (N_PTS + 1) + j_) * C_IN + cb_ + slog_ * 8, \
                        &Plds[BUF][Lb_ * 8]);                                       \
            gload_lds16(wt + (size_t)(o0 + row_) * KDIM + k0_ + slog_ * 8,          \
                        &Wlds[BUF][Lb_ * 8]);                                       \
        }                                                                           \
    }

    STAGE(0, 0)
    __syncthreads();                          // vmcnt(0) drain: buf0 ready

    for (int it = 0; it < 16; ++it) {
        const int cur = it & 1;
        if (it + 1 < 16) STAGE(cur ^ 1, it + 1)   // prefetch next K-step
#pragma unroll
        for (int ks = 0; ks < 2; ++ks) {
            bf16x8 wf[2], pf[4];
#pragma unroll
            for (int f = 0; f < 2; ++f) {
                int orow = wo * 32 + f * 16 + (lane & 15);
                int slw = (ks * 4 + (lane >> 4)) ^ (orow & 7);
                wf[f] = *(const bf16x8*)&Wlds[cur][orow * 64 + slw * 8];
            }
#pragma unroll
            for (int q = 0; q < 4; ++q) {
                int nrow = wn * 64 + q * 16 + (lane & 15);
                int slp = (ks * 4 + (lane >> 4)) ^ (nrow & 7);
                pf[q] = *(const bf16x8*)&Plds[cur][nrow * 64 + slp * 8];
            }
#pragma unroll
            for (int f = 0; f < 2; ++f)
#pragma unroll
                for (int q = 0; q < 4; ++q)
                    acc[f][q] = __builtin_amdgcn_mfma_f32_16x16x32_bf16(
                        wf[f], pf[q], acc[f][q], 0, 0, 0);
        }
        __syncthreads();                      // next buf staged + this buf's reads done
    }
#undef STAGE

#pragma unroll
    for (int f = 0; f < 2; ++f) {
        int o = o0 + wo * 32 + f * 16 + (lane >> 4) * 4;
#pragma unroll
        for (int q = 0; q < 4; ++q) {
            int n = nb + wn * 64 + q * 16 + (lane & 15);
#pragma unroll
            for (int r = 0; r < 4; ++r) {
                out[((size_t)b * C_OUT + o + r) * N_PTS + n] = acc[f][q][r] + bias[o + r];
            }
        }
    }
}

extern "C" void kernel_launch(void* const* d_in, const int* in_sizes, int n_in,
                              void* d_out, int out_size, void* d_ws, size_t ws_size,
                              hipStream_t stream) {
    const float* x    = (const float*)d_in[0];
    const float* pcs  = (const float*)d_in[1];
    const float* w    = (const float*)d_in[2];
    const float* bias = (const float*)d_in[3];

    // ws layout (bytes) — total 5,252,112 (proven-safe range):
    char* base = (char*)d_ws;
    float4* sp4 = (float4*)base;                                    //       0 (262,144)
    unsigned short* xbf = (unsigned short*)(base + 262144);         // 4,195,328
    unsigned short* wt  = (unsigned short*)(base + 4457472);        //   524,288
    unsigned short* idxu = (unsigned short*)(base + 4981760);       //   262,144
    int* cellstart = (int*)(base + 5243904);                        //     8,208
    float* out = (float*)d_out;

    // TIMING PROBE (this round only): fused_prep launched twice, idempotent.
    // dur_us(R14) - dur_us(R13) = P + gap -> direct measurement of prep's true cost.
    hipLaunchKernelGGL(fused_prep, dim3(520),  dim3(256), 0, stream,
                       w, wt, x, xbf, pcs, sp4, cellstart);
    hipLaunchKernelGGL(fused_prep, dim3(520),  dim3(256), 0, stream,
                       w, wt, x, xbf, pcs, sp4, cellstart);
    hipLaunchKernelGGL(bq_grid,    dim3(4096), dim3(256), 0, stream,
                       sp4, cellstart, idxu);
    hipLaunchKernelGGL(pconv_gemm, dim3(256),  dim3(512), 0, stream,
                       xbf, wt, idxu, bias, out);
}

// Round 15
// 43.817 us; speedup vs baseline: 1.1732x; 1.1732x over previous
//
#include <hip/hip_runtime.h>
#include <stdint.h>

#define N_PTS 4096
#define BATCH 4
#define C_IN  128
#define C_OUT 256
#define KDIM  1024   // 8 active slots * 128 channels (octant-7 slot provably always zero)
#define NCELL 512    // 8x8x8 spatial grid, cell 0.125 >= radius 0.12
#define BIGJ  0x3fffffff

typedef __attribute__((ext_vector_type(8))) __bf16 bf16x8;
typedef __attribute__((ext_vector_type(4))) float  f32x4;

__device__ inline void gload_lds16(const void* g, void* l) {
    __builtin_amdgcn_global_load_lds(
        (__attribute__((address_space(1))) void*)(void*)(uintptr_t)g,
        (__attribute__((address_space(3))) void*)l, 16, 0, 0);
}

__device__ inline unsigned short f2bf(float v) {
    uint32_t u = __builtin_bit_cast(uint32_t, v);
    return (unsigned short)((u + 0x7fffu + ((u >> 16) & 1u)) >> 16);   // RTNE
}

// reference-exact sq = ((x*x + y*y) + z*z), no FMA contraction
__device__ inline float sq_exact(float x, float y, float z) {
    return __fadd_rn(__fadd_rn(__fmul_rn(x, x), __fmul_rn(y, y)), __fmul_rn(z, z));
}

__device__ inline int cell_of(float x, float y, float z) {
    int cx = (int)(x * 8.0f); cx = min(max(cx, 0), 7);
    int cy = (int)(y * 8.0f); cy = min(max(cy, 0), 7);
    int cz = (int)(z * 8.0f); cz = min(max(cz, 0), 7);
    return (cx << 6) | (cy << 3) | cz;
}

// ---------------- kernel 1: fused prep (unchanged from round 13) ----------------
__global__ __launch_bounds__(256) void fused_prep(const float* __restrict__ w,
                                                  unsigned short* __restrict__ wt,
                                                  const float* __restrict__ x,
                                                  unsigned short* __restrict__ xbf,
                                                  const float* __restrict__ pcs,
                                                  float4* __restrict__ sp4,
                                                  int* __restrict__ cellstart) {
    const int bid = blockIdx.x;
    const int tid = threadIdx.x;

    if (bid < 4) {
        // ---- grid build for batch b: count -> prefix -> scatter (LDS) ----
        __shared__ int scnt[NCELL];                   // counts -> cursors
        __shared__ int pairs[256];
        const int b = bid;
        const float* pb = pcs + (size_t)b * 3 * N_PTS;
        for (int i = tid; i < NCELL; i += 256) scnt[i] = 0;
        float px[16], py[16], pz[16];
#pragma unroll
        for (int k = 0; k < 16; ++k) {
            int n = k * 256 + tid;
            px[k] = pb[n]; py[k] = pb[N_PTS + n]; pz[k] = pb[2 * N_PTS + n];
        }
        __syncthreads();
#pragma unroll
        for (int k = 0; k < 16; ++k)
            atomicAdd(&scnt[cell_of(px[k], py[k], pz[k])], 1);
        __syncthreads();
        const int a0 = scnt[2 * tid], a1 = scnt[2 * tid + 1];
        pairs[tid] = a0 + a1;
        __syncthreads();
        for (int off = 1; off < 256; off <<= 1) {
            int v = (tid >= off) ? pairs[tid - off] : 0;
            __syncthreads();
            pairs[tid] += v;
            __syncthreads();
        }
        const int epair = pairs[tid] - (a0 + a1);     // exclusive pair prefix
        cellstart[b * 513 + 2 * tid]     = epair;
        cellstart[b * 513 + 2 * tid + 1] = epair + a0;
        scnt[2 * tid]     = epair;                    // cursors
        scnt[2 * tid + 1] = epair + a0;
        if (tid == 255) cellstart[b * 513 + 512] = epair + a0 + a1;
        __syncthreads();
#pragma unroll
        for (int k = 0; k < 16; ++k) {
            int n = k * 256 + tid;
            int slot = atomicAdd(&scnt[cell_of(px[k], py[k], pz[k])], 1);
            sp4[(b << 12) + slot] =
                make_float4(px[k], py[k], pz[k], __builtin_bit_cast(float, n));
        }
    } else if (bid < 260) {
        // ---- weight transpose: one block per o ----
        __shared__ float wrow[1152];
        const int o = bid - 4;
        for (int i = tid; i < 1152; i += 256)
            wrow[i] = w[(size_t)o * 1152 + i];        // fully coalesced
        __syncthreads();
        const int k0 = tid * 4;                       // 4 consecutive kappa
        unsigned int lo =
            (unsigned int)f2bf(wrow[((k0    ) & 127) * 9 + ((k0    ) >> 7)]) |
            ((unsigned int)f2bf(wrow[((k0 + 1) & 127) * 9 + ((k0 + 1) >> 7)]) << 16);
        unsigned int hi =
            (unsigned int)f2bf(wrow[((k0 + 2) & 127) * 9 + ((k0 + 2) >> 7)]) |
            ((unsigned int)f2bf(wrow[((k0 + 3) & 127) * 9 + ((k0 + 3) >> 7)]) << 16);
        *(uint2*)&wt[(size_t)o * 1024 + k0] = make_uint2(lo, hi);
    } else {
        // ---- feature transpose: float4 loads, c-major tile ----
        __shared__ __attribute__((aligned(16))) unsigned short tcj[128 * 66];
        const int bb = bid - 260;
        const int b = bb / 65;
        const int j0 = (bb % 65) * 64;
        if (j0 < N_PTS) {
            const int p = tid & 15;                   // j4 = p*4 (16 lanes cover 64 j)
            const int g = tid >> 4;                   // 16 channel-groups
#pragma unroll
            for (int it = 0; it < 8; ++it) {
                const int cc = it * 16 + g;
                float4 v = *(const float4*)&x[((size_t)b * C_IN + cc) * N_PTS + j0 + p * 4];
                unsigned int lo = (unsigned int)f2bf(v.x) | ((unsigned int)f2bf(v.y) << 16);
                unsigned int hi = (unsigned int)f2bf(v.z) | ((unsigned int)f2bf(v.w) << 16);
                *(uint2*)&tcj[cc * 66 + p * 4] = make_uint2(lo, hi);
            }
            __syncthreads();
#pragma unroll
            for (int i = 0; i < 8; ++i) {
                int idx = i * 256 + tid;              // 2048 uint2: 64 j x 32 c-quads
                int row = idx >> 5, cq = idx & 31;
                unsigned int lo =
                    (unsigned int)tcj[(cq * 4 + 0) * 66 + row] |
                    ((unsigned int)tcj[(cq * 4 + 1) * 66 + row] << 16);
                unsigned int hi =
                    (unsigned int)tcj[(cq * 4 + 2) * 66 + row] |
                    ((unsigned int)tcj[(cq * 4 + 3) * 66 + row] << 16);
                *(uint2*)&xbf[((size_t)b * (N_PTS + 1) + j0 + row) * C_IN + cq * 4] =
                    make_uint2(lo, hi);
            }
        } else {
            // zeros row j = 4096 (empty-octant gather target)
            for (int i = tid; i < C_IN; i += 256)
                xbf[((size_t)b * (N_PTS + 1) + N_PTS) * C_IN + i] = 0;
        }
    }
}

// ---------------- kernel 2: grid ball query — 4 centers per wave (16 lanes each) ----
// Lane-group g of each wave owns sorted slot base+g. Same per-center math as the
// proven R9 kernel (order-free octant mins; 31-cap rank check), but per-wave
// prologue (run-table chain) and shfl-epilogue amortize over 4 centers, the
// candidate loop deepens 4x (better latency pipelining), and each 64-lane ballot
// serves 4 centers at once. Waves: 16384 -> 4096.
__global__ __launch_bounds__(256) void bq_grid(const float4* __restrict__ sp4,
                                               const int* __restrict__ cellstart,
                                               unsigned short* __restrict__ idxu) {
    __shared__ int lists[16 * 128];                   // 4 waves x 4 groups x 128
    const int tid = threadIdx.x;
    const int wid = tid >> 6, lane = tid & 63;
    const int grp = lane >> 4;                        // 16-lane group 0..3
    const int gl  = lane & 15;
    // XCD-chunked bijective swizzle (1024 blocks, 8 XCDs): each XCD owns a
    // contiguous run of 2048 sorted slots.
    const int lb = ((blockIdx.x & 7) << 7) | (blockIdx.x >> 3);
    const int gslot = (lb << 4) | (wid << 2) | grp;   // global slot id 0..16383
    const int b = gslot >> 12;
    const int sidx = gslot & 4095;                    // cell-sorted slot
    const float4* sp = sp4 + ((size_t)b << 12);
    const int* cs = cellstart + b * 513;
    const float4 cp = sp[sidx];
    const float cxf = cp.x, cyf = cp.y, czf = cp.z;
    const int n = __builtin_bit_cast(int, cp.w);      // original center index
    const float csq = sq_exact(cxf, cyf, czf);        // bit-identical to reference
    const float r2 = (float)(0.12 * 0.12);

    int cx = min(max((int)(cxf * 8.0f), 0), 7);
    int cy = min(max((int)(cyf * 8.0f), 0), 7);
    int cz = min(max((int)(czf * 8.0f), 0), 7);
    const int zlo = max(cz - 1, 0), zhi = min(cz + 1, 7);

    // 9-run table (per-lane; uniform within each 16-lane group — rule #20 names)
#define RUN(k, dx, dy)                                                              \
    int rs##k = 0, ln##k = 0;                                                       \
    {                                                                               \
        int gx = cx + (dx), gy = cy + (dy);                                         \
        if (gx >= 0 && gx <= 7 && gy >= 0 && gy <= 7) {                             \
            int cb_ = (gx << 6) | (gy << 3);                                        \
            rs##k = cs[cb_ + zlo];                                                  \
            ln##k = cs[cb_ + zhi + 1] - rs##k;                                      \
        }                                                                           \
    }
    RUN(0, -1, -1) RUN(1, -1, 0) RUN(2, -1, 1)
    RUN(3,  0, -1) RUN(4,  0, 0) RUN(5,  0, 1)
    RUN(6,  1, -1) RUN(7,  1, 0) RUN(8,  1, 1)
#undef RUN
    const int c1 = ln0;
    const int c2 = c1 + ln1;
    const int c3 = c2 + ln2;
    const int c4 = c3 + ln3;
    const int c5 = c4 + ln4;
    const int c6 = c5 + ln5;
    const int c7 = c6 + ln6;
    const int c8 = c7 + ln7;
    const int TT = c8 + ln8;                          // group's candidate count

    // stream position -> cell-sorted slot (static cndmask chain, clamped safe)
#define CAND_IDX(T, OUTI)                                                           \
    {                                                                               \
        const int t_ = (T);                                                         \
        int i_ = rs0 + t_;                                                          \
        i_ = (t_ >= c1) ? (rs1 + t_ - c1) : i_;                                     \
        i_ = (t_ >= c2) ? (rs2 + t_ - c2) : i_;                                     \
        i_ = (t_ >= c3) ? (rs3 + t_ - c3) : i_;                                     \
        i_ = (t_ >= c4) ? (rs4 + t_ - c4) : i_;                                     \
        i_ = (t_ >= c5) ? (rs5 + t_ - c5) : i_;                                     \
        i_ = (t_ >= c6) ? (rs6 + t_ - c6) : i_;                                     \
        i_ = (t_ >= c7) ? (rs7 + t_ - c7) : i_;                                     \
        i_ = (t_ >= c8) ? (rs8 + t_ - c8) : i_;                                     \
        OUTI = (t_ < TT) ? i_ : rs4;   /* rs4 = center's own cell, always valid */  \
    }

    int f0 = BIGJ, f1 = BIGJ, f2 = BIGJ, f3 = BIGJ, f4 = BIGJ, f5 = BIGJ, f6 = BIGJ;
    int cnt = 0;
    int* lst = &lists[(wid * 4 + grp) * 128];
    const unsigned long long gbase = 0xFFFFull << (grp << 4);   // group lane mask
    const unsigned long long ltm = (1ull << lane) - 1ull;

    int ic0;
    CAND_IDX(gl, ic0)
    float4 p_cur = sp[ic0];                           // prologue load (TT >= 1 always)

    for (int t0 = 0; ; ) {
        int icn;
        CAND_IDX(t0 + 16 + gl, icn)
        const float4 p_nxt = sp[icn];                 // prefetch next chunk

        const bool valid = (t0 + gl) < TT;
        const float4 p = p_cur;
        const int j = __builtin_bit_cast(int, p.w);
        const float psq = sq_exact(p.x, p.y, p.z);    // bit-identical to reference
        float dot = __fadd_rn(__fadd_rn(__fmul_rn(cxf, p.x), __fmul_rn(cyf, p.y)),
                              __fmul_rn(czf, p.z));
        float dd = __fsub_rn(__fadd_rn(csq, psq), __fmul_rn(2.0f, dot));
        const bool ok = valid && (dd <= r2) && (j != n);
        const unsigned long long m = __ballot(ok) & gbase;   // this group's matches
        if (m) {
            int pos = cnt + __popcll(m & ltm);
            if (ok && pos < 128) lst[pos] = j;
            cnt += __popcll(m);                        // group-uniform
            const int oct = ((p.x >= cxf) ? 4 : 0) + ((p.y >= cyf) ? 2 : 0)
                          + ((p.z >= czf) ? 1 : 0);
            const int key = ok ? j : BIGJ;
            f0 = (oct == 0) ? min(f0, key) : f0;
            f1 = (oct == 1) ? min(f1, key) : f1;
            f2 = (oct == 2) ? min(f2, key) : f2;
            f3 = (oct == 3) ? min(f3, key) : f3;
            f4 = (oct == 4) ? min(f4, key) : f4;
            f5 = (oct == 5) ? min(f5, key) : f5;
            f6 = (oct == 6) ? min(f6, key) : f6;
        }
        t0 += 16;
        if (!__any(t0 < TT)) break;                   // wave-uniform exit
        p_cur = p_nxt;
    }
#undef CAND_IDX

    // octant-min reduce within the 16-lane group
#define WMIN16(V)                                                                   \
    V = min(V, __shfl_xor(V, 8, 64)); V = min(V, __shfl_xor(V, 4, 64));             \
    V = min(V, __shfl_xor(V, 2, 64)); V = min(V, __shfl_xor(V, 1, 64));
    WMIN16(f0) WMIN16(f1) WMIN16(f2) WMIN16(f3) WMIN16(f4) WMIN16(f5) WMIN16(f6)
#undef WMIN16

    if (cnt > 31) {
        // rank check: f_o survives iff #{matches j < f_o} <= 30. Per-lane partial
        // counts over 8 list entries, packed 7x9-bit, one 16-lane shfl-reduce.
        const int c2_ = min(cnt, 128);
        unsigned long long packed = 0;
#pragma unroll
        for (int k = 0; k < 8; ++k) {
            const int e = (gl + k * 16 < c2_) ? lst[gl + k * 16] : BIGJ;
            packed += (unsigned long long)(e < f0)
                    + ((unsigned long long)(e < f1) << 9)
                    + ((unsigned long long)(e < f2) << 18)
                    + ((unsigned long long)(e < f3) << 27)
                    + ((unsigned long long)(e < f4) << 36)
                    + ((unsigned long long)(e < f5) << 45)
                    + ((unsigned long long)(e < f6) << 54);
        }
        packed += __shfl_xor(packed, 8, 64);
        packed += __shfl_xor(packed, 4, 64);
        packed += __shfl_xor(packed, 2, 64);
        packed += __shfl_xor(packed, 1, 64);
        f0 = (((packed      ) & 511) <= 30) ? f0 : BIGJ;
        f1 = (((packed >>  9) & 511) <= 30) ? f1 : BIGJ;
        f2 = (((packed >> 18) & 511) <= 30) ? f2 : BIGJ;
        f3 = (((packed >> 27) & 511) <= 30) ? f3 : BIGJ;
        f4 = (((packed >> 36) & 511) <= 30) ? f4 : BIGJ;
        f5 = (((packed >> 45) & 511) <= 30) ? f5 : BIGJ;
        f6 = (((packed >> 54) & 511) <= 30) ? f6 : BIGJ;
    }

    int v = n;                                        // gl 0: center index
    if (gl == 1) v = f0;
    if (gl == 2) v = f1;
    if (gl == 3) v = f2;
    if (gl == 4) v = f3;
    if (gl == 5) v = f4;
    if (gl == 6) v = f5;
    if (gl == 7) v = f6;
    if (v > N_PTS) v = N_PTS;                         // BIGJ -> zeros row
    if (gl < 8) idxu[((size_t)((b << 12) | n)) * 8 + gl] = (unsigned short)v;
}

// ---------------- kernel 3: gathered GEMM (unchanged from round 12) ----------------
__global__ __launch_bounds__(512) void pconv_gemm(const unsigned short* __restrict__ xbf,
                                                  const unsigned short* __restrict__ wt,
                                                  const unsigned short* __restrict__ idxu,
                                                  const float* __restrict__ bias,
                                                  float* __restrict__ out) {
    __shared__ __attribute__((aligned(16))) unsigned short Plds[2][128 * 64];
    __shared__ __attribute__((aligned(16))) unsigned short Wlds[2][128 * 64];
    __shared__ unsigned short jlds[128 * 8];
    const int tid = threadIdx.x;
    const int tile = ((blockIdx.x & 7) << 5) | (blockIdx.x >> 3);   // XCD-chunked, bijective
    const int tm = tile >> 1, tn = tile & 1;  // 128 M-tiles x 2 N-tiles
    const int g0 = tm * 128;                 // global point-row base
    const int b  = g0 >> 12;
    const int nb = g0 & 4095;
    const int o0 = tn * 128;
    const int wid = tid >> 6, lane = tid & 63;
    const int wo = wid >> 1, wn = wid & 1;   // wave -> 32 o-rows x 64 n-cols

    // hoist all gather indices for this block (1024 u16, coalesced)
    for (int i = tid; i < 1024; i += 512) jlds[i] = idxu[(size_t)g0 * 8 + i];
    __syncthreads();

    f32x4 acc[2][4] = {};

#define STAGE(BUF, IT)                                                              \
    {                                                                               \
        const int k0_ = (IT) << 6;                                                  \
        const int slot_ = (IT) >> 1;                                                \
        const int cb_ = ((IT) & 1) << 6;                                            \
        _Pragma("unroll")                                                           \
        for (int i_ = 0; i_ < 2; ++i_) {                                            \
            const int Lb_ = i_ * 512 + wid * 64;                                    \
            const int row_ = (Lb_ + lane) >> 3;                                     \
            const int slog_ = (lane & 7) ^ (row_ & 7);                              \
            int j_ = jlds[row_ * 8 + slot_];                                        \
            gload_lds16(xbf + ((size_t)b * (N_PTS + 1) + j_) * C_IN + cb_ + slog_ * 8, \
                        &Plds[BUF][Lb_ * 8]);                                       \
            gload_lds16(wt + (size_t)(o0 + row_) * KDIM + k0_ + slog_ * 8,          \
                        &Wlds[BUF][Lb_ * 8]);                                       \
        }                                                                           \
    }

    STAGE(0, 0)
    __syncthreads();                          // vmcnt(0) drain: buf0 ready

    for (int it = 0; it < 16; ++it) {
        const int cur = it & 1;
        if (it + 1 < 16) STAGE(cur ^ 1, it + 1)   // prefetch next K-step
#pragma unroll
        for (int ks = 0; ks < 2; ++ks) {
            bf16x8 wf[2], pf[4];
#pragma unroll
            for (int f = 0; f < 2; ++f) {
                int orow = wo * 32 + f * 16 + (lane & 15);
                int slw = (ks * 4 + (lane >> 4)) ^ (orow & 7);
                wf[f] = *(const bf16x8*)&Wlds[cur][orow * 64 + slw * 8];
            }
#pragma unroll
            for (int q = 0; q < 4; ++q) {
                int nrow = wn * 64 + q * 16 + (lane & 15);
                int slp = (ks * 4 + (lane >> 4)) ^ (nrow & 7);
                pf[q] = *(const bf16x8*)&Plds[cur][nrow * 64 + slp * 8];
            }
#pragma unroll
            for (int f = 0; f < 2; ++f)
#pragma unroll
                for (int q = 0; q < 4; ++q)
                    acc[f][q] = __builtin_amdgcn_mfma_f32_16x16x32_bf16(
                        wf[f], pf[q], acc[f][q], 0, 0, 0);
        }
        __syncthreads();                      // next buf staged + this buf's reads done
    }
#undef STAGE

#pragma unroll
    for (int f = 0; f < 2; ++f) {
        int o = o0 + wo * 32 + f * 16 + (lane >> 4) * 4;
#pragma unroll
        for (int q = 0; q < 4; ++q) {
            int n = nb + wn * 64 + q * 16 + (lane & 15);
#pragma unroll
            for (int r = 0; r < 4; ++r) {
                out[((size_t)b * C_OUT + o + r) * N_PTS + n] = acc[f][q][r] + bias[o + r];
            }
        }
    }
}

extern "C" void kernel_launch(void* const* d_in, const int* in_sizes, int n_in,
                              void* d_out, int out_size, void* d_ws, size_t ws_size,
                              hipStream_t stream) {
    const float* x    = (const float*)d_in[0];
    const float* pcs  = (const float*)d_in[1];
    const float* w    = (const float*)d_in[2];
    const float* bias = (const float*)d_in[3];

    // ws layout (bytes) — total 5,252,112 (proven-safe range):
    char* base = (char*)d_ws;
    float4* sp4 = (float4*)base;                                    //       0 (262,144)
    unsigned short* xbf = (unsigned short*)(base + 262144);         // 4,195,328
    unsigned short* wt  = (unsigned short*)(base + 4457472);        //   524,288
    unsigned short* idxu = (unsigned short*)(base + 4981760);       //   262,144
    int* cellstart = (int*)(base + 5243904);                        //     8,208
    float* out = (float*)d_out;

    hipLaunchKernelGGL(fused_prep, dim3(520),  dim3(256), 0, stream,
                       w, wt, x, xbf, pcs, sp4, cellstart);
    hipLaunchKernelGGL(bq_grid,    dim3(1024), dim3(256), 0, stream,
                       sp4, cellstart, idxu);
    hipLaunchKernelGGL(pconv_gemm, dim3(256),  dim3(512), 0, stream,
                       xbf, wt, idxu, bias, out);
}

// Round 16
// 41.373 us; speedup vs baseline: 1.2425x; 1.0591x over previous
//
#include <hip/hip_runtime.h>
#include <stdint.h>

#define N_PTS 4096
#define BATCH 4
#define C_IN  128
#define C_OUT 256
#define KDIM  1024   // 8 active slots * 128 channels (octant-7 slot provably always zero)
#define NCELL 512    // 8x8x8 spatial grid, cell 0.125 >= radius 0.12
#define BIGJ  0x3fffffff

typedef __attribute__((ext_vector_type(8))) __bf16 bf16x8;
typedef __attribute__((ext_vector_type(4))) float  f32x4;

__device__ inline void gload_lds16(const void* g, void* l) {
    __builtin_amdgcn_global_load_lds(
        (__attribute__((address_space(1))) void*)(void*)(uintptr_t)g,
        (__attribute__((address_space(3))) void*)l, 16, 0, 0);
}

__device__ inline unsigned short f2bf(float v) {
    uint32_t u = __builtin_bit_cast(uint32_t, v);
    return (unsigned short)((u + 0x7fffu + ((u >> 16) & 1u)) >> 16);   // RTNE
}

// reference-exact sq = ((x*x + y*y) + z*z), no FMA contraction
__device__ inline float sq_exact(float x, float y, float z) {
    return __fadd_rn(__fadd_rn(__fmul_rn(x, x), __fmul_rn(y, y)), __fmul_rn(z, z));
}

__device__ inline int cell_of(float x, float y, float z) {
    int cx = (int)(x * 8.0f); cx = min(max(cx, 0), 7);
    int cy = (int)(y * 8.0f); cy = min(max(cy, 0), 7);
    int cz = (int)(z * 8.0f); cz = min(max(cz, 0), 7);
    return (cx << 6) | (cy << 3) | cz;
}

// ---------------- kernel 1: fused prep (unchanged from round 13) ----------------
__global__ __launch_bounds__(256) void fused_prep(const float* __restrict__ w,
                                                  unsigned short* __restrict__ wt,
                                                  const float* __restrict__ x,
                                                  unsigned short* __restrict__ xbf,
                                                  const float* __restrict__ pcs,
                                                  float4* __restrict__ sp4,
                                                  int* __restrict__ cellstart) {
    const int bid = blockIdx.x;
    const int tid = threadIdx.x;

    if (bid < 4) {
        // ---- grid build for batch b: count -> prefix -> scatter (LDS) ----
        __shared__ int scnt[NCELL];                   // counts -> cursors
        __shared__ int pairs[256];
        const int b = bid;
        const float* pb = pcs + (size_t)b * 3 * N_PTS;
        for (int i = tid; i < NCELL; i += 256) scnt[i] = 0;
        float px[16], py[16], pz[16];
#pragma unroll
        for (int k = 0; k < 16; ++k) {
            int n = k * 256 + tid;
            px[k] = pb[n]; py[k] = pb[N_PTS + n]; pz[k] = pb[2 * N_PTS + n];
        }
        __syncthreads();
#pragma unroll
        for (int k = 0; k < 16; ++k)
            atomicAdd(&scnt[cell_of(px[k], py[k], pz[k])], 1);
        __syncthreads();
        const int a0 = scnt[2 * tid], a1 = scnt[2 * tid + 1];
        pairs[tid] = a0 + a1;
        __syncthreads();
        for (int off = 1; off < 256; off <<= 1) {
            int v = (tid >= off) ? pairs[tid - off] : 0;
            __syncthreads();
            pairs[tid] += v;
            __syncthreads();
        }
        const int epair = pairs[tid] - (a0 + a1);     // exclusive pair prefix
        cellstart[b * 513 + 2 * tid]     = epair;
        cellstart[b * 513 + 2 * tid + 1] = epair + a0;
        scnt[2 * tid]     = epair;                    // cursors
        scnt[2 * tid + 1] = epair + a0;
        if (tid == 255) cellstart[b * 513 + 512] = epair + a0 + a1;
        __syncthreads();
#pragma unroll
        for (int k = 0; k < 16; ++k) {
            int n = k * 256 + tid;
            int slot = atomicAdd(&scnt[cell_of(px[k], py[k], pz[k])], 1);
            sp4[(b << 12) + slot] =
                make_float4(px[k], py[k], pz[k], __builtin_bit_cast(float, n));
        }
    } else if (bid < 260) {
        // ---- weight transpose: one block per o ----
        __shared__ float wrow[1152];
        const int o = bid - 4;
        for (int i = tid; i < 1152; i += 256)
            wrow[i] = w[(size_t)o * 1152 + i];        // fully coalesced
        __syncthreads();
        const int k0 = tid * 4;                       // 4 consecutive kappa
        unsigned int lo =
            (unsigned int)f2bf(wrow[((k0    ) & 127) * 9 + ((k0    ) >> 7)]) |
            ((unsigned int)f2bf(wrow[((k0 + 1) & 127) * 9 + ((k0 + 1) >> 7)]) << 16);
        unsigned int hi =
            (unsigned int)f2bf(wrow[((k0 + 2) & 127) * 9 + ((k0 + 2) >> 7)]) |
            ((unsigned int)f2bf(wrow[((k0 + 3) & 127) * 9 + ((k0 + 3) >> 7)]) << 16);
        *(uint2*)&wt[(size_t)o * 1024 + k0] = make_uint2(lo, hi);
    } else {
        // ---- feature transpose: float4 loads, c-major tile ----
        __shared__ __attribute__((aligned(16))) unsigned short tcj[128 * 66];
        const int bb = bid - 260;
        const int b = bb / 65;
        const int j0 = (bb % 65) * 64;
        if (j0 < N_PTS) {
            const int p = tid & 15;                   // j4 = p*4 (16 lanes cover 64 j)
            const int g = tid >> 4;                   // 16 channel-groups
#pragma unroll
            for (int it = 0; it < 8; ++it) {
                const int cc = it * 16 + g;
                float4 v = *(const float4*)&x[((size_t)b * C_IN + cc) * N_PTS + j0 + p * 4];
                unsigned int lo = (unsigned int)f2bf(v.x) | ((unsigned int)f2bf(v.y) << 16);
                unsigned int hi = (unsigned int)f2bf(v.z) | ((unsigned int)f2bf(v.w) << 16);
                *(uint2*)&tcj[cc * 66 + p * 4] = make_uint2(lo, hi);
            }
            __syncthreads();
#pragma unroll
            for (int i = 0; i < 8; ++i) {
                int idx = i * 256 + tid;              // 2048 uint2: 64 j x 32 c-quads
                int row = idx >> 5, cq = idx & 31;
                unsigned int lo =
                    (unsigned int)tcj[(cq * 4 + 0) * 66 + row] |
                    ((unsigned int)tcj[(cq * 4 + 1) * 66 + row] << 16);
                unsigned int hi =
                    (unsigned int)tcj[(cq * 4 + 2) * 66 + row] |
                    ((unsigned int)tcj[(cq * 4 + 3) * 66 + row] << 16);
                *(uint2*)&xbf[((size_t)b * (N_PTS + 1) + j0 + row) * C_IN + cq * 4] =
                    make_uint2(lo, hi);
            }
        } else {
            // zeros row j = 4096 (empty-octant gather target)
            for (int i = tid; i < C_IN; i += 256)
                xbf[((size_t)b * (N_PTS + 1) + N_PTS) * C_IN + i] = 0;
        }
    }
}

// ---------------- kernel 2: grid ball query — 4 centers/wave, 2-deep prefetch -------
__global__ __launch_bounds__(256) void bq_grid(const float4* __restrict__ sp4,
                                               const int* __restrict__ cellstart,
                                               unsigned short* __restrict__ idxu) {
    __shared__ int lists[16 * 128];                   // 4 waves x 4 groups x 128
    const int tid = threadIdx.x;
    const int wid = tid >> 6, lane = tid & 63;
    const int grp = lane >> 4;                        // 16-lane group 0..3
    const int gl  = lane & 15;
    // XCD-chunked bijective swizzle (1024 blocks, 8 XCDs)
    const int lb = ((blockIdx.x & 7) << 7) | (blockIdx.x >> 3);
    const int gslot = (lb << 4) | (wid << 2) | grp;   // global slot id 0..16383
    const int b = gslot >> 12;
    const int sidx = gslot & 4095;                    // cell-sorted slot
    const float4* sp = sp4 + ((size_t)b << 12);
    const int* cs = cellstart + b * 513;
    const float4 cp = sp[sidx];
    const float cxf = cp.x, cyf = cp.y, czf = cp.z;
    const int n = __builtin_bit_cast(int, cp.w);      // original center index
    const float csq = sq_exact(cxf, cyf, czf);        // bit-identical to reference
    const float r2 = (float)(0.12 * 0.12);

    int cx = min(max((int)(cxf * 8.0f), 0), 7);
    int cy = min(max((int)(cyf * 8.0f), 0), 7);
    int cz = min(max((int)(czf * 8.0f), 0), 7);
    const int zlo = max(cz - 1, 0), zhi = min(cz + 1, 7);

#define RUN(k, dx, dy)                                                              \
    int rs##k = 0, ln##k = 0;                                                       \
    {                                                                               \
        int gx = cx + (dx), gy = cy + (dy);                                         \
        if (gx >= 0 && gx <= 7 && gy >= 0 && gy <= 7) {                             \
            int cb_ = (gx << 6) | (gy << 3);                                        \
            rs##k = cs[cb_ + zlo];                                                  \
            ln##k = cs[cb_ + zhi + 1] - rs##k;                                      \
        }                                                                           \
    }
    RUN(0, -1, -1) RUN(1, -1, 0) RUN(2, -1, 1)
    RUN(3,  0, -1) RUN(4,  0, 0) RUN(5,  0, 1)
    RUN(6,  1, -1) RUN(7,  1, 0) RUN(8,  1, 1)
#undef RUN
    const int c1 = ln0;
    const int c2 = c1 + ln1;
    const int c3 = c2 + ln2;
    const int c4 = c3 + ln3;
    const int c5 = c4 + ln4;
    const int c6 = c5 + ln5;
    const int c7 = c6 + ln6;
    const int c8 = c7 + ln7;
    const int TT = c8 + ln8;                          // group's candidate count

#define CAND_IDX(T, OUTI)                                                           \
    {                                                                               \
        const int t_ = (T);                                                         \
        int i_ = rs0 + t_;                                                          \
        i_ = (t_ >= c1) ? (rs1 + t_ - c1) : i_;                                     \
        i_ = (t_ >= c2) ? (rs2 + t_ - c2) : i_;                                     \
        i_ = (t_ >= c3) ? (rs3 + t_ - c3) : i_;                                     \
        i_ = (t_ >= c4) ? (rs4 + t_ - c4) : i_;                                     \
        i_ = (t_ >= c5) ? (rs5 + t_ - c5) : i_;                                     \
        i_ = (t_ >= c6) ? (rs6 + t_ - c6) : i_;                                     \
        i_ = (t_ >= c7) ? (rs7 + t_ - c7) : i_;                                     \
        i_ = (t_ >= c8) ? (rs8 + t_ - c8) : i_;                                     \
        OUTI = (t_ < TT) ? i_ : rs4;   /* rs4 = center's own cell, always valid */  \
    }

    int f0 = BIGJ, f1 = BIGJ, f2 = BIGJ, f3 = BIGJ, f4 = BIGJ, f5 = BIGJ, f6 = BIGJ;
    int cnt = 0;
    int* lst = &lists[(wid * 4 + grp) * 128];
    const unsigned long long gbase = 0xFFFFull << (grp << 4);   // group lane mask
    const unsigned long long ltm = (1ull << lane) - 1ull;

    // 2-deep software pipeline: chunks t and t+16 in flight while processing t
    int icA, icB;
    CAND_IDX(gl, icA)
    CAND_IDX(16 + gl, icB)
    float4 pA = sp[icA];
    float4 pB = sp[icB];

    for (int t0 = 0; ; ) {
        int icC;
        CAND_IDX(t0 + 32 + gl, icC)
        const float4 pC = sp[icC];                    // prefetch chunk t+32

        const bool valid = (t0 + gl) < TT;
        const float4 p = pA;
        const int j = __builtin_bit_cast(int, p.w);
        const float psq = sq_exact(p.x, p.y, p.z);    // bit-identical to reference
        float dot = __fadd_rn(__fadd_rn(__fmul_rn(cxf, p.x), __fmul_rn(cyf, p.y)),
                              __fmul_rn(czf, p.z));
        float dd = __fsub_rn(__fadd_rn(csq, psq), __fmul_rn(2.0f, dot));
        const bool ok = valid && (dd <= r2) && (j != n);
        const unsigned long long m = __ballot(ok) & gbase;   // this group's matches
        if (m) {
            int pos = cnt + __popcll(m & ltm);
            if (ok && pos < 128) lst[pos] = j;
            cnt += __popcll(m);                        // group-uniform
            const int oct = ((p.x >= cxf) ? 4 : 0) + ((p.y >= cyf) ? 2 : 0)
                          + ((p.z >= czf) ? 1 : 0);
            const int key = ok ? j : BIGJ;
            f0 = (oct == 0) ? min(f0, key) : f0;
            f1 = (oct == 1) ? min(f1, key) : f1;
            f2 = (oct == 2) ? min(f2, key) : f2;
            f3 = (oct == 3) ? min(f3, key) : f3;
            f4 = (oct == 4) ? min(f4, key) : f4;
            f5 = (oct == 5) ? min(f5, key) : f5;
            f6 = (oct == 6) ? min(f6, key) : f6;
        }
        t0 += 16;
        if (!__any(t0 < TT)) break;                   // wave-uniform exit
        pA = pB; pB = pC;
    }
#undef CAND_IDX

#define WMIN16(V)                                                                   \
    V = min(V, __shfl_xor(V, 8, 64)); V = min(V, __shfl_xor(V, 4, 64));             \
    V = min(V, __shfl_xor(V, 2, 64)); V = min(V, __shfl_xor(V, 1, 64));
    WMIN16(f0) WMIN16(f1) WMIN16(f2) WMIN16(f3) WMIN16(f4) WMIN16(f5) WMIN16(f6)
#undef WMIN16

    if (cnt > 31) {
        // rank check: f_o survives iff #{matches j < f_o} <= 30 (packed 7x9-bit)
        const int c2_ = min(cnt, 128);
        unsigned long long packed = 0;
#pragma unroll
        for (int k = 0; k < 8; ++k) {
            const int e = (gl + k * 16 < c2_) ? lst[gl + k * 16] : BIGJ;
            packed += (unsigned long long)(e < f0)
                    + ((unsigned long long)(e < f1) << 9)
                    + ((unsigned long long)(e < f2) << 18)
                    + ((unsigned long long)(e < f3) << 27)
                    + ((unsigned long long)(e < f4) << 36)
                    + ((unsigned long long)(e < f5) << 45)
                    + ((unsigned long long)(e < f6) << 54);
        }
        packed += __shfl_xor(packed, 8, 64);
        packed += __shfl_xor(packed, 4, 64);
        packed += __shfl_xor(packed, 2, 64);
        packed += __shfl_xor(packed, 1, 64);
        f0 = (((packed      ) & 511) <= 30) ? f0 : BIGJ;
        f1 = (((packed >>  9) & 511) <= 30) ? f1 : BIGJ;
        f2 = (((packed >> 18) & 511) <= 30) ? f2 : BIGJ;
        f3 = (((packed >> 27) & 511) <= 30) ? f3 : BIGJ;
        f4 = (((packed >> 36) & 511) <= 30) ? f4 : BIGJ;
        f5 = (((packed >> 45) & 511) <= 30) ? f5 : BIGJ;
        f6 = (((packed >> 54) & 511) <= 30) ? f6 : BIGJ;
    }

    int v = n;                                        // gl 0: center index
    if (gl == 1) v = f0;
    if (gl == 2) v = f1;
    if (gl == 3) v = f2;
    if (gl == 4) v = f3;
    if (gl == 5) v = f4;
    if (gl == 6) v = f5;
    if (gl == 7) v = f6;
    if (v > N_PTS) v = N_PTS;                         // BIGJ -> zeros row
    if (gl < 8) idxu[((size_t)((b << 12) | n)) * 8 + gl] = (unsigned short)v;
}

// ---------------- kernel 3: gathered GEMM — 4-buf counted-vmcnt pipeline (T4) -------
// Stages it+1, it+2 stay in flight across barriers; per-iter wait is vmcnt(8)
// (= 2 stages x 4 loads/thread), NEVER a full drain in the main loop. One raw
// s_barrier per iter; stage target buf[(it+2)&3] was last read 2 barrier
// generations ago -> race-free. Memory-clobber asm brackets the barrier so LDS
// reads can't hoist above it.
__global__ __launch_bounds__(512) void pconv_gemm(const unsigned short* __restrict__ xbf,
                                                  const unsigned short* __restrict__ wt,
                                                  const unsigned short* __restrict__ idxu,
                                                  const float* __restrict__ bias,
                                                  float* __restrict__ out) {
    __shared__ __attribute__((aligned(16))) unsigned short Plds[4][128 * 64];
    __shared__ __attribute__((aligned(16))) unsigned short Wlds[4][128 * 64];
    __shared__ unsigned short jlds[128 * 8];
    const int tid = threadIdx.x;
    const int tile = ((blockIdx.x & 7) << 5) | (blockIdx.x >> 3);   // XCD-chunked, bijective
    const int tm = tile >> 1, tn = tile & 1;  // 128 M-tiles x 2 N-tiles
    const int g0 = tm * 128;                 // global point-row base
    const int b  = g0 >> 12;
    const int nb = g0 & 4095;
    const int o0 = tn * 128;
    const int wid = tid >> 6, lane = tid & 63;
    const int wo = wid >> 1, wn = wid & 1;   // wave -> 32 o-rows x 64 n-cols

    // hoist all gather indices for this block (1024 u16, coalesced)
    for (int i = tid; i < 1024; i += 512) jlds[i] = idxu[(size_t)g0 * 8 + i];
    __syncthreads();

    f32x4 acc[2][4] = {};

#define STAGE(BUF, IT)                                                              \
    {                                                                               \
        const int k0_ = (IT) << 6;                                                  \
        const int slot_ = (IT) >> 1;                                                \
        const int cb_ = ((IT) & 1) << 6;                                            \
        _Pragma("unroll")                                                           \
        for (int i_ = 0; i_ < 2; ++i_) {                                            \
            const int Lb_ = i_ * 512 + wid * 64;                                    \
            const int row_ = (Lb_ + lane) >> 3;                                     \
            const int slog_ = (lane & 7) ^ (row_ & 7);                              \
            int j_ = jlds[row_ * 8 + slot_];                                        \
            gload_lds16(xbf + ((size_t)b * (N_PTS + 1) + j_) * C_IN + cb_ + slog_ * 8, \
                        &Plds[BUF][Lb_ * 8]);                                       \
            gload_lds16(wt + (size_t)(o0 + row_) * KDIM + k0_ + slog_ * 8,          \
                        &Wlds[BUF][Lb_ * 8]);                                       \
        }                                                                           \
    }

    STAGE(0, 0)
    STAGE(1, 1)

    for (int it = 0; it < 16; ++it) {
        const int cur = it & 3;
        if (it + 2 < 16) STAGE((it + 2) & 3, it + 2)   // keep 2 stages in flight
        // counted wait: stage(it) done; stages it+1 (+ it+2 if issued) remain
        if (it <= 13)      asm volatile("s_waitcnt vmcnt(8)" ::: "memory");
        else if (it == 14) asm volatile("s_waitcnt vmcnt(4)" ::: "memory");
        else               asm volatile("s_waitcnt vmcnt(0)" ::: "memory");
        __builtin_amdgcn_s_barrier();
        asm volatile("" ::: "memory");        // LDS reads below stay below barrier
#pragma unroll
        for (int ks = 0; ks < 2; ++ks) {
            bf16x8 wf[2], pf[4];
#pragma unroll
            for (int f = 0; f < 2; ++f) {
                int orow = wo * 32 + f * 16 + (lane & 15);
                int slw = (ks * 4 + (lane >> 4)) ^ (orow & 7);
                wf[f] = *(const bf16x8*)&Wlds[cur][orow * 64 + slw * 8];
            }
#pragma unroll
            for (int q = 0; q < 4; ++q) {
                int nrow = wn * 64 + q * 16 + (lane & 15);
                int slp = (ks * 4 + (lane >> 4)) ^ (nrow & 7);
                pf[q] = *(const bf16x8*)&Plds[cur][nrow * 64 + slp * 8];
            }
#pragma unroll
            for (int f = 0; f < 2; ++f)
#pragma unroll
                for (int q = 0; q < 4; ++q)
                    acc[f][q] = __builtin_amdgcn_mfma_f32_16x16x32_bf16(
                        wf[f], pf[q], acc[f][q], 0, 0, 0);
        }
    }
#undef STAGE

#pragma unroll
    for (int f = 0; f < 2; ++f) {
        int o = o0 + wo * 32 + f * 16 + (lane >> 4) * 4;
#pragma unroll
        for (int q = 0; q < 4; ++q) {
            int n = nb + wn * 64 + q * 16 + (lane & 15);
#pragma unroll
            for (int r = 0; r < 4; ++r) {
                out[((size_t)b * C_OUT + o + r) * N_PTS + n] = acc[f][q][r] + bias[o + r];
            }
        }
    }
}

extern "C" void kernel_launch(void* const* d_in, const int* in_sizes, int n_in,
                              void* d_out, int out_size, void* d_ws, size_t ws_size,
                              hipStream_t stream) {
    const float* x    = (const float*)d_in[0];
    const float* pcs  = (const float*)d_in[1];
    const float* w    = (const float*)d_in[2];
    const float* bias = (const float*)d_in[3];

    // ws layout (bytes) — total 5,252,112 (proven-safe range):
    char* base = (char*)d_ws;
    float4* sp4 = (float4*)base;                                    //       0 (262,144)
    unsigned short* xbf = (unsigned short*)(base + 262144);         // 4,195,328
    unsigned short* wt  = (unsigned short*)(base + 4457472);        //   524,288
    unsigned short* idxu = (unsigned short*)(base + 4981760);       //   262,144
    int* cellstart = (int*)(base + 5243904);                        //     8,208
    float* out = (float*)d_out;

    hipLaunchKernelGGL(fused_prep, dim3(520),  dim3(256), 0, stream,
                       w, wt, x, xbf, pcs, sp4, cellstart);
    hipLaunchKernelGGL(bq_grid,    dim3(1024), dim3(256), 0, stream,
                       sp4, cellstart, idxu);
    hipLaunchKernelGGL(pconv_gemm, dim3(256),  dim3(512), 0, stream,
                       xbf, wt, idxu, bias, out);
}